// Round 3
// baseline (32079.187 us; speedup 1.0000x reference)
//
#include <hip/hip_runtime.h>
#include <stdint.h>

// Problem constants (setup_inputs: B,L,D,H,A = 128,256,128,256,128)
#define LL   256
#define BB   128
#define DD   128
#define HH   256
#define H2C  512
#define H3C  768
#define ADIM 128
#define NCAT 896          // 768 (W) + 128 (W_action_1) concatenated columns
#define MROWS 32768       // L*B
#define EPSV 1e-5f
#define BW   16           // batches per scan workgroup

typedef __attribute__((ext_vector_type(8))) short short8;   // 8 bf16 (4 VGPRs)
typedef __attribute__((ext_vector_type(4))) float f32x4;
typedef unsigned short u16;

__device__ __forceinline__ u16 f2bf(float f) {
    unsigned int u = __float_as_uint(f);
    u = (u + 0x7FFFu + ((u >> 16) & 1u)) >> 16;   // RNE bf16 (finite data only)
    return (u16)u;
}
__device__ __forceinline__ float bf2f(u16 h) {
    return __uint_as_float(((unsigned int)h) << 16);
}
__device__ __forceinline__ float hsg(float x) {   // hard_sigmoid
    return fminf(fmaxf(0.2f * x + 0.5f, 0.f), 1.f);
}

// ---------------------------------------------------------------- small init
__global__ void init_flags(int* flags) {
    int i = threadIdx.x;
    if (i < 8) flags[i] = 0;      // done[0..3], anyb[0..3]
}

__global__ void build_bcat(const float* __restrict__ b_, const float* __restrict__ ba1,
                           float* __restrict__ bcat) {
    int i = blockIdx.x * 256 + threadIdx.x;
    if (i < NCAT) bcat[i] = (i < H3C) ? b_[i] : ba1[i - H3C];
}

// dmcur = mask.T ; apcur = 0 ; eos[t][b] = dm0[t][b] * (1 - dm0[t+1][b])
__global__ void init_seq(const float* __restrict__ mask, float* __restrict__ apcur,
                         float* __restrict__ dmcur, float* __restrict__ eosb) {
    int i = blockIdx.x * 256 + threadIdx.x;    // over L*B
    if (i >= MROWS) return;
    int t = i >> 7, b = i & 127;
    float dm  = mask[b * LL + t];
    float nxt = (t < LL - 1) ? mask[b * LL + t + 1] : 0.f;
    dmcur[i] = dm;
    apcur[i] = 0.f;
    eosb[i]  = dm * (1.f - nxt);
}

// ---------------------------------------------------------------- conversions
// generic f32 -> (hi,lo) bf16 split, same layout
__global__ void conv_hilo(const float* __restrict__ in, u16* __restrict__ hi,
                          u16* __restrict__ lo, int n, const int* __restrict__ skip) {
    if (skip && *skip) return;
    int i = blockIdx.x * 256 + threadIdx.x;
    if (i >= n) return;
    float v = in[i];
    u16 h = f2bf(v);
    hi[i] = h;
    lo[i] = f2bf(v - bf2f(h));
}

// Wcat = [W | W_action_1] (256 x 896), stored TRANSPOSED [c][k] for MFMA B-frags
__global__ void conv_wcatT(const float* __restrict__ W, const float* __restrict__ Wa1,
                           u16* __restrict__ hi, u16* __restrict__ lo) {
    int i = blockIdx.x * 256 + threadIdx.x;   // over NCAT*HH
    if (i >= NCAT * HH) return;
    int c = i / HH, k = i % HH;
    float v = (c < H3C) ? W[k * H3C + c] : Wa1[k * ADIM + (c - H3C)];
    u16 h = f2bf(v);
    hi[i] = h;
    lo[i] = f2bf(v - bf2f(h));
}

// W_emb (128 x 256) transposed -> [c][k], K=128
__global__ void conv_wembT(const float* __restrict__ We,
                           u16* __restrict__ hi, u16* __restrict__ lo) {
    int i = blockIdx.x * 256 + threadIdx.x;   // over HH*DD
    if (i >= HH * DD) return;
    int c = i / DD, k = i % DD;
    float v = We[k * HH + c];
    u16 h = f2bf(v);
    hi[i] = h;
    lo[i] = f2bf(v - bf2f(h));
}

// Scan B-operands in exact fragment order. UT1 = [U[:, :512] | Ua1] (40 n-tiles),
// UT2 = U[:, 512:768] (16 n-tiles). Element (nt,kt,lane,j): col = nt*16+(lane&15),
// k = kt*32+(lane>>4)*8+j. Flat index ((nt*8+kt)*64+lane)*8+j.
__global__ void conv_ut(const float* __restrict__ U, const float* __restrict__ Ua1,
                        u16* __restrict__ u1h, u16* __restrict__ u1l,
                        u16* __restrict__ u2h, u16* __restrict__ u2l) {
    int i = blockIdx.x * 256 + threadIdx.x;    // (40+16)*512 = 28672
    if (i >= 56 * 512) return;
    int which = (i >= 40 * 512) ? 1 : 0;
    int j = which ? i - 40 * 512 : i;
    int nt = j >> 9, rem = j & 511, kt = rem >> 6, ln = rem & 63;
    int colb = nt * 16 + (ln & 15);
    int k0 = kt * 32 + (ln >> 4) * 8;
    u16* dh = (which ? u2h : u1h) + (size_t)j * 8;
    u16* dl = (which ? u2l : u1l) + (size_t)j * 8;
    #pragma unroll
    for (int jj = 0; jj < 8; ++jj) {
        int k = k0 + jj;
        float v;
        if (!which) v = (colb < H2C) ? U[k * H3C + colb] : Ua1[k * ADIM + colb - H2C];
        else        v = U[k * H3C + H2C + colb];
        u16 h = f2bf(v);
        dh[jj] = h;
        dl[jj] = f2bf(v - bf2f(h));
    }
}

// ---------------------------------------------------------------- split-bf16 MFMA GEMM
__global__ __launch_bounds__(256)
void gemm_bf16split(const u16* __restrict__ Ahi, const u16* __restrict__ Alo,
                    const u16* __restrict__ Bhi, const u16* __restrict__ Blo,
                    float* __restrict__ C, int Mi, int Ni, int Ki,
                    const float* __restrict__ bias, int remap, const int* __restrict__ skip)
{
    if (skip && *skip) return;
    __shared__ __attribute__((aligned(16))) u16 sA[2][128 * 32];  // [hi/lo][m][k]
    __shared__ __attribute__((aligned(16))) u16 sB[2][128 * 32];  // [hi/lo][n][k]
    const int tid = threadIdx.x, lane = tid & 63, wave = tid >> 6;
    const int bm = blockIdx.y * 128, bn = blockIdx.x * 128;
    const int wm = (wave >> 1) * 64, wn = (wave & 1) * 64;
    f32x4 acc[4][4] = {};
    for (int kk = 0; kk < Ki; kk += 32) {
        __syncthreads();
        #pragma unroll
        for (int j = 0; j < 2; ++j) {
            int cidx = tid + j * 256;                     // 0..511 16B chunks
            int r = cidx >> 2, kc = (cidx & 3) << 3;
            *(uint4*)&sA[0][cidx * 8] = *(const uint4*)&Ahi[(size_t)(bm + r) * Ki + kk + kc];
            *(uint4*)&sA[1][cidx * 8] = *(const uint4*)&Alo[(size_t)(bm + r) * Ki + kk + kc];
            *(uint4*)&sB[0][cidx * 8] = *(const uint4*)&Bhi[(size_t)(bn + r) * Ki + kk + kc];
            *(uint4*)&sB[1][cidx * 8] = *(const uint4*)&Blo[(size_t)(bn + r) * Ki + kk + kc];
        }
        __syncthreads();
        short8 a0[4], a1[4], b0[4], b1[4];
        int k8 = (lane >> 4) << 3;
        #pragma unroll
        for (int i = 0; i < 4; ++i) {
            int rA = wm + i * 16 + (lane & 15);
            a0[i] = *(short8*)&sA[0][rA * 32 + k8];
            a1[i] = *(short8*)&sA[1][rA * 32 + k8];
            int rB = wn + i * 16 + (lane & 15);
            b0[i] = *(short8*)&sB[0][rB * 32 + k8];
            b1[i] = *(short8*)&sB[1][rB * 32 + k8];
        }
        #pragma unroll
        for (int i = 0; i < 4; ++i)
        #pragma unroll
        for (int j = 0; j < 4; ++j) {
            acc[i][j] = __builtin_amdgcn_mfma_f32_16x16x32_bf16(a0[i], b0[j], acc[i][j], 0, 0, 0);
            acc[i][j] = __builtin_amdgcn_mfma_f32_16x16x32_bf16(a0[i], b1[j], acc[i][j], 0, 0, 0);
            acc[i][j] = __builtin_amdgcn_mfma_f32_16x16x32_bf16(a1[i], b0[j], acc[i][j], 0, 0, 0);
        }
    }
    int r4 = (lane >> 4) << 2, cl = lane & 15;
    #pragma unroll
    for (int i = 0; i < 4; ++i)
    #pragma unroll
    for (int j = 0; j < 4; ++j)
    #pragma unroll
    for (int q = 0; q < 4; ++q) {
        int row = bm + wm + i * 16 + r4 + q;
        int col = bn + wn + j * 16 + cl;
        float v = acc[i][j][q];
        if (bias) v += bias[col];
        if (remap) {   // embed: A-rows are (b,l); write to xcur[(t*B + b)]
            int b_ = row >> 8, t_ = row & 255;
            C[(size_t)(t_ * BB + b_) * Ni + col] = v;
        } else {
            C[(size_t)row * Ni + col] = v;
        }
    }
}

// ---------------------------------------------------------------- row LN (in place on raw)
__global__ __launch_bounds__(256)
void ln_rows(float* __restrict__ raw, const float* __restrict__ bcat,
             const float* __restrict__ gam, const float* __restrict__ bet,
             const int* __restrict__ skip)
{
    if (skip && *skip) return;
    int wave = threadIdx.x >> 6, lane = threadIdx.x & 63;
    size_t row = (size_t)blockIdx.x * 4 + wave;
    float* base = raw + row * NCAT;
    float v[14];
    #pragma unroll
    for (int j = 0; j < 14; ++j) v[j] = base[lane + j * 64] + bcat[lane + j * 64];
    float s = 0.f;
    #pragma unroll
    for (int j = 0; j < 12; ++j) s += v[j];
    #pragma unroll
    for (int o = 32; o; o >>= 1) s += __shfl_down(s, o);
    s = __shfl(s, 0);
    float mean = s / 768.f;
    float q = 0.f;
    #pragma unroll
    for (int j = 0; j < 12; ++j) { float d = v[j] - mean; q += d * d; }
    #pragma unroll
    for (int o = 32; o; o >>= 1) q += __shfl_down(q, o);
    q = __shfl(q, 0);
    float inv = 1.f / (sqrtf(q / 768.f + EPSV) + EPSV);
    #pragma unroll
    for (int j = 0; j < 12; ++j) {
        int c = lane + j * 64;
        base[c] = gam[c] * ((v[j] - mean) * inv) + bet[c];
    }
    #pragma unroll
    for (int j = 12; j < 14; ++j) base[lane + j * 64] = v[j];
}

// ---------------------------------------------------------------- MFMA scan helpers
__device__ __forceinline__ void ldb(short8* dh, short8* dl,
                                    const u16* __restrict__ GH, const u16* __restrict__ GL,
                                    int nt, int lane) {
    const u16* ph = GH + (size_t)nt * 4096 + lane * 8;
    const u16* pl = GL + (size_t)nt * 4096 + lane * 8;
    #pragma unroll
    for (int kt = 0; kt < 8; ++kt) {
        dh[kt] = *(const short8*)(ph + kt * 512);
        dl[kt] = *(const short8*)(pl + kt * 512);
    }
}
__device__ __forceinline__ void tile3(f32x4& acc, const short8* ah, const short8* al,
                                      const short8* bh, const short8* bl) {
    #pragma unroll
    for (int kt = 0; kt < 8; ++kt) {
        acc = __builtin_amdgcn_mfma_f32_16x16x32_bf16(ah[kt], bh[kt], acc, 0, 0, 0);
        acc = __builtin_amdgcn_mfma_f32_16x16x32_bf16(ah[kt], bl[kt], acc, 0, 0, 0);
        acc = __builtin_amdgcn_mfma_f32_16x16x32_bf16(al[kt], bh[kt], acc, 0, 0, 0);
    }
}

// ---------------------------------------------------------------- the MFMA scan
// 8 WGs x 16 batches, 512 threads (8 waves). Per step:
//  P1: m1 = h @ U[:, :512] and pol-pre = h @ Ua1 via split-bf16 MFMA (M=16 batches).
//  Gates on tid<16; z/r + rh on all waves; P3: m2 = rh @ U[:,512:768]; P4: combine.
// h kept exact-f32 in LDS; hi/lo bf16 copies feed MFMA A-fragments.
__global__ __launch_bounds__(512)
void scan_mfma(const float* __restrict__ raw,     // [MROWS][896] s1(LN'd)|xa
               const float* __restrict__ xcur,    // [MROWS][256]
               float* __restrict__ hseq,          // [MROWS][256]
               const float* __restrict__ apcur,   // [L*B]
               const float* __restrict__ dmcur,
               const float* __restrict__ eosb,
               float* __restrict__ aseq,
               float* __restrict__ dmseq,
               const u16* __restrict__ UT1h, const u16* __restrict__ UT1l,
               const u16* __restrict__ UT2h, const u16* __restrict__ UT2l,
               const float* __restrict__ W2,      // [128][2]
               const float* __restrict__ b2g,     // [2]
               const float* __restrict__ gam,     // [2][768] full
               const float* __restrict__ bet,
               int llm, int* __restrict__ anyb, const int* __restrict__ skip)
{
    if (skip && *skip) return;
    // swizzled bf16 h/rh: ushort idx = b*256 + (col ^ ((b&7)<<3))
    __shared__ u16 h_hi[BW * 256], h_lo[BW * 256], rh_hi[BW * 256], rh_lo[BW * 256];
    __shared__ float h_f32[BW * 276], z_s[BW * 276];      // stride 276 -> 2-way banks
    __shared__ float g1v[H2C], be1v[H2C], g2v[HH], be2v[HH], w2l[2 * ADIM];
    __shared__ float red1[256], red2[256], red3[256], scal_g[64];
    const int tid = threadIdx.x, lane = tid & 63, w = tid >> 6;
    const int lcol = lane & 15, lrow = lane >> 4;
    const int bofs = blockIdx.x * BW;

    for (int i = tid; i < H2C; i += 512) { g1v[i] = gam[H3C + i]; be1v[i] = bet[H3C + i]; }
    for (int i = tid; i < HH;  i += 512) { g2v[i] = gam[H3C + H2C + i]; be2v[i] = bet[H3C + H2C + i]; }
    for (int i = tid; i < 2 * ADIM; i += 512) w2l[i] = W2[i];
    for (int i = tid; i < BW * 276; i += 512) h_f32[i] = 0.f;
    for (int i = tid; i < BW * 256; i += 512) { h_hi[i] = 0; h_lo[i] = 0; }
    float a_tm1 = 0.f, dm_tm1 = 0.f, b20 = 0.f, b21 = 0.f;  // tid<16 only
    if (tid < 16) { b20 = b2g[0]; b21 = b2g[1]; }
    int anyLocal = 0;
    __syncthreads();

    for (int t = 0; t < LL; ++t) {
        const float* rawt = raw + (size_t)(t * BB + bofs) * NCAT;
        float sc_ap = 0.f, sc_dm = 0.f, sc_sdm = 1.f, sc_sem = 0.f;
        if (tid < 16) {
            int g = t * BB + bofs + tid;
            sc_ap = apcur[g]; sc_dm = dmcur[g];
            sc_sdm = t ? dmcur[g - BB] : 1.f;
            sc_sem = t ? eosb[g - BB] : 0.f;
        }

        // ---- P1: A-frags from h (prev step), B streamed from L2 (double-buffered)
        short8 ah[8], al[8];
        #pragma unroll
        for (int kt = 0; kt < 8; ++kt) {
            int idx = lcol * 256 + ((kt * 32 + lrow * 8) ^ ((lcol & 7) << 3));
            ah[kt] = *(const short8*)&h_hi[idx];
            al[kt] = *(const short8*)&h_lo[idx];
        }
        f32x4 am[4] = {}; f32x4 aa = {};
        short8 b0h[8], b0l[8], b1h[8], b1l[8];
        ldb(b0h, b0l, UT1h, UT1l, w * 4 + 0, lane);
        ldb(b1h, b1l, UT1h, UT1l, w * 4 + 1, lane);
        tile3(am[0], ah, al, b0h, b0l);
        ldb(b0h, b0l, UT1h, UT1l, w * 4 + 2, lane);
        tile3(am[1], ah, al, b1h, b1l);
        ldb(b1h, b1l, UT1h, UT1l, w * 4 + 3, lane);
        tile3(am[2], ah, al, b0h, b0l);
        ldb(b0h, b0l, UT1h, UT1l, 32 + w, lane);
        tile3(am[3], ah, al, b1h, b1l);
        tile3(aa, ah, al, b0h, b0l);

        // scattered per-lane loads: s1 (z/r part) and xa
        float xa_[4], s1zr[4][4];
        #pragma unroll
        for (int q = 0; q < 4; ++q) {
            int bq = lrow * 4 + q;
            xa_[q] = rawt[(size_t)bq * NCAT + H3C + w * 16 + lcol];
            #pragma unroll
            for (int i = 0; i < 4; ++i)
                s1zr[i][q] = rawt[(size_t)bq * NCAT + (w * 4 + i) * 16 + lcol];
        }
        // m1 stats partials (per batch: sum, sumsq over this wave's 64 cols)
        float s_[4], qq_[4];
        #pragma unroll
        for (int q = 0; q < 4; ++q) {
            float a0 = am[0][q], a1 = am[1][q], a2 = am[2][q], a3 = am[3][q];
            s_[q] = a0 + a1 + a2 + a3;
            qq_[q] = a0 * a0 + a1 * a1 + a2 * a2 + a3 * a3;
        }
        #pragma unroll
        for (int m = 1; m < 16; m <<= 1)
            #pragma unroll
            for (int q = 0; q < 4; ++q) { s_[q] += __shfl_xor(s_[q], m); qq_[q] += __shfl_xor(qq_[q], m); }
        if (lcol == 0)
            #pragma unroll
            for (int q = 0; q < 4; ++q) {
                int b = lrow * 4 + q;
                red1[(w * 16 + b) * 2] = s_[q]; red1[(w * 16 + b) * 2 + 1] = qq_[q];
            }
        // pol partials: relu(xa + h@Ua1) * W2
        float l0_[4], l1_[4];
        #pragma unroll
        for (int q = 0; q < 4; ++q) {
            float pv = fmaxf(xa_[q] + aa[q], 0.f);
            l0_[q] = pv * w2l[(w * 16 + lcol) * 2];
            l1_[q] = pv * w2l[(w * 16 + lcol) * 2 + 1];
        }
        #pragma unroll
        for (int m = 1; m < 16; m <<= 1)
            #pragma unroll
            for (int q = 0; q < 4; ++q) { l0_[q] += __shfl_xor(l0_[q], m); l1_[q] += __shfl_xor(l1_[q], m); }
        if (lcol == 0)
            #pragma unroll
            for (int q = 0; q < 4; ++q) {
                int b = lrow * 4 + q;
                red2[(w * 16 + b) * 2] = l0_[q]; red2[(w * 16 + b) * 2 + 1] = l1_[q];
            }
        __syncthreads();  // B1

        // ---- gates on tid<16 (one batch each)
        if (tid < 16) {
            float l0 = b20, l1 = b21;
            #pragma unroll
            for (int w8 = 0; w8 < 8; ++w8) { l0 += red2[(w8 * 16 + tid) * 2]; l1 += red2[(w8 * 16 + tid) * 2 + 1]; }
            float p0 = fminf(expf(l0), 1000.f);
            float p1 = fminf(expf(l1), 1000.f);
            float act = (p0 <= p1) ? 1.f : 0.f;
            if (sc_ap  > 0.f) act = 1.f;
            if (llm    > 0)   act = 1.f;
            if (sc_sem > 0.f) act = 0.f;
            float both   = (1.f - sc_ap) * sc_dm * act * dm_tm1;
            float h_only = dm_tm1 * act * (sc_ap + (1.f - sc_ap) * (1.f - sc_dm));
            float x_only = sc_dm * (1.f - sc_ap) * (1.f - act + act * (1.f - dm_tm1));
            float dmnew  = both + x_only + h_only;
            float a_out  = (sc_sdm > 0.f) ? act : a_tm1;
            int g = t * BB + bofs + tid;
            aseq[g] = a_out; dmseq[g] = dmnew;
            a_tm1 = a_out; dm_tm1 = dmnew;
            anyLocal |= (both > 0.f) ? 1 : 0;
            scal_g[tid * 4 + 0] = both; scal_g[tid * 4 + 1] = h_only;
            scal_g[tid * 4 + 2] = x_only; scal_g[tid * 4 + 3] = sc_dm;
        }
        // ---- m1 LN scalars (redundant per-thread) then z / rh
        float mean1[4], inv1[4];
        #pragma unroll
        for (int q = 0; q < 4; ++q) {
            int b = lrow * 4 + q; float s = 0.f, sq = 0.f;
            #pragma unroll
            for (int w8 = 0; w8 < 8; ++w8) { s += red1[(w8 * 16 + b) * 2]; sq += red1[(w8 * 16 + b) * 2 + 1]; }
            float mean = s * (1.f / 512.f);
            float var  = sq * (1.f / 512.f) - mean * mean;
            mean1[q] = mean; inv1[q] = 1.f / (sqrtf(var + EPSV) + EPSV);
        }
        if (w < 4) {   // z columns 0..255
            #pragma unroll
            for (int i = 0; i < 4; ++i) {
                int c = (w * 4 + i) * 16 + lcol;
                float g1c = g1v[c], b1c = be1v[c];
                #pragma unroll
                for (int q = 0; q < 4; ++q) {
                    int b = lrow * 4 + q;
                    float s2 = g1c * ((am[i][q] - mean1[q]) * inv1[q]) + b1c;
                    z_s[b * 276 + c] = hsg(s1zr[i][q] + s2);
                }
            }
        } else {       // r columns 256..511 -> rh (bf16 hi/lo, swizzled)
            #pragma unroll
            for (int i = 0; i < 4; ++i) {
                int c = (w * 4 + i) * 16 + lcol;
                int c2 = c - 256;
                float g1c = g1v[c], b1c = be1v[c];
                #pragma unroll
                for (int q = 0; q < 4; ++q) {
                    int b = lrow * 4 + q;
                    float s2 = g1c * ((am[i][q] - mean1[q]) * inv1[q]) + b1c;
                    float rr = hsg(s1zr[i][q] + s2);
                    float rhv = rr * h_f32[b * 276 + c2];
                    u16 hi_ = f2bf(rhv);
                    int si = b * 256 + (c2 ^ ((b & 7) << 3));
                    rh_hi[si] = hi_;
                    rh_lo[si] = f2bf(rhv - bf2f(hi_));
                }
            }
        }
        __syncthreads();  // B2

        // ---- P3: m2 = rh @ U[:,512:768]; this wave owns cols 32w..32w+31
        short8 ch[8], cl2[8];
        #pragma unroll
        for (int kt = 0; kt < 8; ++kt) {
            int idx = lcol * 256 + ((kt * 32 + lrow * 8) ^ ((lcol & 7) << 3));
            ch[kt]  = *(const short8*)&rh_hi[idx];
            cl2[kt] = *(const short8*)&rh_lo[idx];
        }
        float s1t[2][4], xt[2][4];
        #pragma unroll
        for (int j = 0; j < 2; ++j)
            #pragma unroll
            for (int q = 0; q < 4; ++q) {
                int bq = lrow * 4 + q;
                int c2 = (w * 2 + j) * 16 + lcol;
                s1t[j][q] = rawt[(size_t)bq * NCAT + H2C + c2];
                xt[j][q]  = xcur[(size_t)(t * BB + bofs + bq) * HH + c2];
            }
        f32x4 a2[2] = {};
        ldb(b0h, b0l, UT2h, UT2l, w * 2 + 0, lane);
        ldb(b1h, b1l, UT2h, UT2l, w * 2 + 1, lane);
        tile3(a2[0], ch, cl2, b0h, b0l);
        tile3(a2[1], ch, cl2, b1h, b1l);
        // m2 stats partials
        #pragma unroll
        for (int q = 0; q < 4; ++q) {
            float v0 = a2[0][q], v1 = a2[1][q];
            s_[q] = v0 + v1; qq_[q] = v0 * v0 + v1 * v1;
        }
        #pragma unroll
        for (int m = 1; m < 16; m <<= 1)
            #pragma unroll
            for (int q = 0; q < 4; ++q) { s_[q] += __shfl_xor(s_[q], m); qq_[q] += __shfl_xor(qq_[q], m); }
        if (lcol == 0)
            #pragma unroll
            for (int q = 0; q < 4; ++q) {
                int b = lrow * 4 + q;
                red3[(w * 16 + b) * 2] = s_[q]; red3[(w * 16 + b) * 2 + 1] = qq_[q];
            }
        __syncthreads();  // B3

        // ---- P4: combine, update h
        float mean2[4], inv2[4];
        #pragma unroll
        for (int q = 0; q < 4; ++q) {
            int b = lrow * 4 + q; float s = 0.f, sq = 0.f;
            #pragma unroll
            for (int w8 = 0; w8 < 8; ++w8) { s += red3[(w8 * 16 + b) * 2]; sq += red3[(w8 * 16 + b) * 2 + 1]; }
            float mean = s * (1.f / 256.f);
            float var  = sq * (1.f / 256.f) - mean * mean;
            mean2[q] = mean; inv2[q] = 1.f / (sqrtf(var + EPSV) + EPSV);
        }
        #pragma unroll
        for (int j = 0; j < 2; ++j) {
            int c2 = (w * 2 + j) * 16 + lcol;
            float g2c = g2v[c2], b2c = be2v[c2];
            #pragma unroll
            for (int q = 0; q < 4; ++q) {
                int b = lrow * 4 + q;
                float ln2 = g2c * ((a2[j][q] - mean2[q]) * inv2[q]) + b2c;
                float tc = tanhf(s1t[j][q] + ln2);
                float zv = z_s[b * 276 + c2];
                float hp = h_f32[b * 276 + c2];
                float hc = zv * hp + (1.f - zv) * tc;
                float hn = scal_g[b * 4 + 0] * hc + scal_g[b * 4 + 1] * hp + scal_g[b * 4 + 2] * xt[j][q];
                hn = (scal_g[b * 4 + 3] > 0.f) ? hn : hp;
                h_f32[b * 276 + c2] = hn;
                u16 hi_ = f2bf(hn);
                int si = b * 256 + (c2 ^ ((b & 7) << 3));
                h_hi[si] = hi_;
                h_lo[si] = f2bf(hn - bf2f(hi_));
                hseq[(size_t)(t * BB + bofs + b) * HH + c2] = hn;
            }
        }
        __syncthreads();  // B4 (h ready for next step)
    }
    if (tid < 16 && anyLocal) atomicOr(anyb, 1);
}

// ---------------------------------------------------------------- commit (vstep glue)
__global__ void commit_pass(float* __restrict__ xcur, const float* __restrict__ hseq,
                            float* __restrict__ apcur, const float* __restrict__ aseq,
                            float* __restrict__ dmcur, const float* __restrict__ dmseq,
                            const int* __restrict__ donep, int* __restrict__ donep1,
                            const int* __restrict__ anyb)
{
    size_t i = (size_t)blockIdx.x * 256 + threadIdx.x;
    int done = *donep;
    if (blockIdx.x == 0 && threadIdx.x == 0)
        *donep1 = done | ((*anyb == 0) ? 1 : 0);
    if (done) return;
    if (i < (size_t)MROWS * HH) xcur[i] = hseq[i];
    if (i < MROWS) {
        int t = (int)(i >> 7);
        apcur[i] = (t < LL - 1) ? aseq[i + BB] : 0.f;
        dmcur[i] = dmseq[i];
    }
}

__global__ void write_out(const float* __restrict__ hseq, float* __restrict__ outp) {
    int i = blockIdx.x * 256 + threadIdx.x;   // 32768 = B*H
    if (i >= BB * HH) return;
    int b = i >> 8, h = i & 255;
    outp[i] = hseq[((size_t)(LL - 1) * BB + b) * HH + h];
}

// ---------------------------------------------------------------- launcher
static inline size_t alignUp(size_t v) { return (v + 255) & ~(size_t)255; }

extern "C" void kernel_launch(void* const* d_in, const int* in_sizes, int n_in,
                              void* d_out, int out_size, void* d_ws, size_t ws_size,
                              hipStream_t stream) {
    (void)in_sizes; (void)n_in; (void)out_size; (void)ws_size;
    const float* x     = (const float*)d_in[0];
    const float* mask  = (const float*)d_in[1];
    const float* W_emb = (const float*)d_in[3];
    const float* b_emb = (const float*)d_in[4];
    const float* W     = (const float*)d_in[5];
    const float* U     = (const float*)d_in[6];
    const float* bvec  = (const float*)d_in[7];
    const float* Wa1   = (const float*)d_in[8];
    const float* Ua1   = (const float*)d_in[9];
    const float* ba1   = (const float*)d_in[10];
    const float* W2    = (const float*)d_in[11];
    const float* b2    = (const float*)d_in[12];
    const float* gam   = (const float*)d_in[13];
    const float* bet   = (const float*)d_in[14];
    float* outp = (float*)d_out;

    char* ws = (char*)d_ws;
    size_t off = 0;
    auto take = [&](size_t bytes) { char* p = ws + off; off = alignUp(off + bytes); return p; };
    float* raw  = (float*)take((size_t)MROWS * NCAT * 4);     // 117.4 MB
    float* xcur = (float*)take((size_t)MROWS * HH * 4);       // 33.5 MB
    float* hseq = (float*)take((size_t)MROWS * HH * 4);       // 33.5 MB
    u16* Ahi = (u16*)take((size_t)MROWS * HH * 2);            // 16.8 MB
    u16* Alo = (u16*)take((size_t)MROWS * HH * 2);
    u16* WcT_hi = (u16*)take((size_t)NCAT * HH * 2);
    u16* WcT_lo = (u16*)take((size_t)NCAT * HH * 2);
    u16* WeT_hi = (u16*)take((size_t)HH * DD * 2);
    u16* WeT_lo = (u16*)take((size_t)HH * DD * 2);
    u16* UT1h = (u16*)take((size_t)40 * 512 * 8 * 2);         // 320 KB
    u16* UT1l = (u16*)take((size_t)40 * 512 * 8 * 2);
    u16* UT2h = (u16*)take((size_t)16 * 512 * 8 * 2);         // 128 KB
    u16* UT2l = (u16*)take((size_t)16 * 512 * 8 * 2);
    float* apcur = (float*)take((size_t)MROWS * 4);
    float* dmcur = (float*)take((size_t)MROWS * 4);
    float* eosb  = (float*)take((size_t)MROWS * 4);
    float* aseq  = (float*)take((size_t)MROWS * 4);
    float* dmseq = (float*)take((size_t)MROWS * 4);
    float* bcat  = (float*)take((size_t)NCAT * 4);
    int* flags   = (int*)take(64);
    int* done = flags;        // done[0..3]
    int* anyb = flags + 4;    // anyb[0..3]

    init_flags<<<1, 64, 0, stream>>>(flags);
    build_bcat<<<4, 256, 0, stream>>>(bvec, ba1, bcat);
    conv_wcatT<<<(NCAT * HH + 255) / 256, 256, 0, stream>>>(W, Wa1, WcT_hi, WcT_lo);
    conv_wembT<<<(HH * DD + 255) / 256, 256, 0, stream>>>(W_emb, WeT_hi, WeT_lo);
    conv_ut<<<112, 256, 0, stream>>>(U, Ua1, UT1h, UT1l, UT2h, UT2l);
    init_seq<<<MROWS / 256, 256, 0, stream>>>(mask, apcur, dmcur, eosb);

    // embed: xcur[(t,b)] = x[(b,l)] @ W_emb + b_emb
    conv_hilo<<<(MROWS * DD) / 256, 256, 0, stream>>>(x, Ahi, Alo, MROWS * DD, nullptr);
    gemm_bf16split<<<dim3(HH / 128, MROWS / 128), 256, 0, stream>>>(
        Ahi, Alo, WeT_hi, WeT_lo, xcur, MROWS, HH, DD, b_emb, 1, nullptr);

    for (int p = 0; p < 4; ++p) {
        const int* skip = (p == 1 || p == 2) ? &done[p] : nullptr;
        conv_hilo<<<(MROWS * HH) / 256, 256, 0, stream>>>(xcur, Ahi, Alo, MROWS * HH, skip);
        gemm_bf16split<<<dim3(NCAT / 128, MROWS / 128), 256, 0, stream>>>(
            Ahi, Alo, WcT_hi, WcT_lo, raw, MROWS, NCAT, HH, nullptr, 0, skip);
        ln_rows<<<MROWS / 4, 256, 0, stream>>>(raw, bcat, gam, bet, skip);
        scan_mfma<<<BB / BW, 512, 0, stream>>>(raw, xcur, hseq, apcur, dmcur, eosb,
                                               aseq, dmseq, UT1h, UT1l, UT2h, UT2l,
                                               W2, b2, gam, bet,
                                               (p == 3) ? 1 : 0, &anyb[p], skip);
        if (p < 3)
            commit_pass<<<(MROWS * HH) / 256, 256, 0, stream>>>(
                xcur, hseq, apcur, aseq, dmcur, dmseq, &done[p], &done[p + 1], &anyb[p]);
    }
    write_out<<<(BB * HH) / 256, 256, 0, stream>>>(hseq, outp);
}